// Round 1
// baseline (611.404 us; speedup 1.0000x reference)
//
#include <hip/hip_runtime.h>
#include <stdint.h>

#define B_    4
#define N_    2048
#define DIM_  1024
#define H_    16
#define DH_   64
#define BN_   (B_ * N_)        // 8192 rows
#define QKVN_ (3 * H_ * DH_)   // 3072 qkv cols

typedef unsigned short u16;
typedef __attribute__((ext_vector_type(8))) __bf16 bf16x8;
typedef __attribute__((ext_vector_type(8))) short  short8;
typedef __attribute__((ext_vector_type(4))) float  f32x4;
typedef __attribute__((ext_vector_type(4))) u16    u16x4;

__device__ inline u16 f2bf(float f) {
    union { float f; uint32_t u; } v; v.f = f;
    uint32_t r = v.u + 0x7fffu + ((v.u >> 16) & 1u);   // RNE
    return (u16)(r >> 16);
}
__device__ inline float bf2f(u16 u) {
    union { uint32_t u; float f; } v; v.u = ((uint32_t)u) << 16;
    return v.f;
}

// ---------------- elementwise cast fp32 -> bf16 ----------------
__global__ __launch_bounds__(256) void cast_f32_bf16(const float* __restrict__ in,
                                                     u16* __restrict__ out, int n4) {
    int i = blockIdx.x * blockDim.x + threadIdx.x;
    int stride = gridDim.x * blockDim.x;
    for (; i < n4; i += stride) {
        float4 v = reinterpret_cast<const float4*>(in)[i];
        u16x4 o;
        o.x = f2bf(v.x); o.y = f2bf(v.y); o.z = f2bf(v.z); o.w = f2bf(v.w);
        reinterpret_cast<u16x4*>(out)[i] = o;
    }
}

// -------- cast + transpose: in[R][C] fp32 -> out[C][R] bf16 --------
__global__ __launch_bounds__(256) void transpose_cast(const float* __restrict__ in,
                                                      u16* __restrict__ out, int R, int C) {
    int gid = blockIdx.x * blockDim.x + threadIdx.x;
    int total = C * (R / 4);
    if (gid >= total) return;
    int n  = gid % C;
    int k4 = (gid / C) * 4;
    u16x4 o;
    o.x = f2bf(in[(size_t)(k4 + 0) * C + n]);
    o.y = f2bf(in[(size_t)(k4 + 1) * C + n]);
    o.z = f2bf(in[(size_t)(k4 + 2) * C + n]);
    o.w = f2bf(in[(size_t)(k4 + 3) * C + n]);
    *reinterpret_cast<u16x4*>(&out[(size_t)n * R + k4]) = o;
}

// ---------------- GEMM: C[M,N] = A[M,K] * BT[N,K]^T ----------------
// 128x128 tile, 256 threads = 4 waves in 2x2, each wave 64x64 via 4x4
// mfma_f32_16x16x32_bf16 fragments. BK=32.
template <bool BF16_OUT>
__global__ __launch_bounds__(256) void gemm_bt(const u16* __restrict__ A,
                                               const u16* __restrict__ BT,
                                               void* __restrict__ Cout,
                                               const float* __restrict__ bias,
                                               int M, int Nn, int K) {
    __shared__ u16 As[128][40];   // +8 pad breaks bank-conflict stride
    __shared__ u16 Bs[128][40];

    const int tid  = threadIdx.x;
    const int m0   = blockIdx.y * 128;
    const int n0   = blockIdx.x * 128;
    const int w    = tid >> 6;
    const int lane = tid & 63;
    const int lr   = lane & 15;   // fragment row/col (low 4 bits)
    const int lg   = lane >> 4;   // k-group (0..3)
    const int wm   = w >> 1;      // wave row (0..1)
    const int wn   = w & 1;       // wave col (0..1)

    f32x4 acc[4][4] = {};

    const int sr = tid >> 2;            // staging row 0..63 (plus +64)
    const int sc = (tid & 3) * 8;       // staging col 0..24 step 8
    const u16* Aptr = A  + (size_t)(m0 + sr) * K + sc;
    const u16* Bptr = BT + (size_t)(n0 + sr) * K + sc;

    for (int kt = 0; kt < K; kt += 32) {
        *reinterpret_cast<short8*>(&As[sr][sc])      = *reinterpret_cast<const short8*>(Aptr + kt);
        *reinterpret_cast<short8*>(&As[sr + 64][sc]) = *reinterpret_cast<const short8*>(Aptr + (size_t)64 * K + kt);
        *reinterpret_cast<short8*>(&Bs[sr][sc])      = *reinterpret_cast<const short8*>(Bptr + kt);
        *reinterpret_cast<short8*>(&Bs[sr + 64][sc]) = *reinterpret_cast<const short8*>(Bptr + (size_t)64 * K + kt);
        __syncthreads();

        bf16x8 af[4], bfr[4];
#pragma unroll
        for (int m = 0; m < 4; m++)
            af[m] = *reinterpret_cast<const bf16x8*>(&As[wm * 64 + m * 16 + lr][lg * 8]);
#pragma unroll
        for (int n = 0; n < 4; n++)
            bfr[n] = *reinterpret_cast<const bf16x8*>(&Bs[wn * 64 + n * 16 + lr][lg * 8]);
#pragma unroll
        for (int m = 0; m < 4; m++)
#pragma unroll
            for (int n = 0; n < 4; n++)
                acc[m][n] = __builtin_amdgcn_mfma_f32_16x16x32_bf16(af[m], bfr[n], acc[m][n], 0, 0, 0);
        __syncthreads();
    }

#pragma unroll
    for (int m = 0; m < 4; m++)
#pragma unroll
        for (int n = 0; n < 4; n++) {
            const int row = m0 + wm * 64 + m * 16 + lg * 4;   // + r
            const int col = n0 + wn * 64 + n * 16 + lr;
#pragma unroll
            for (int r = 0; r < 4; r++) {
                if (BF16_OUT) {
                    ((u16*)Cout)[(size_t)(row + r) * Nn + col] = f2bf(acc[m][n][r]);
                } else {
                    ((float*)Cout)[(size_t)(row + r) * Nn + col] = acc[m][n][r] + bias[col];
                }
            }
        }
}

// ---------------- flash attention ----------------
// grid: (N/64, B*H). 256 threads = 4 waves, each wave owns 16 q-rows.
// KV tiles of 32 rows; online softmax in registers; P via per-wave LDS.
__global__ __launch_bounds__(256) void attn_kernel(const u16* __restrict__ qkv,
                                                   u16* __restrict__ out) {
    __shared__ u16 Ks[32][72];        // K tile  [kv][d]  (+8 pad)
    __shared__ u16 VTs[64][40];       // V tile transposed [d][kv] (+8 pad)
    __shared__ u16 Ps[4][16][40];     // per-wave P [q][kv] (+8 pad)

    const int tid  = threadIdx.x;
    const int w    = tid >> 6;
    const int lane = tid & 63;
    const int lr   = lane & 15;
    const int lg   = lane >> 4;

    const int bh = blockIdx.y;
    const int b  = bh >> 4;
    const int h  = bh & 15;
    const int rowbase = b * N_;
    const int q0 = blockIdx.x * 64;
    const int qoff = h * DH_;

    // Q fragments (scaled by DH^-0.5 = 0.125, exact in bf16)
    bf16x8 qf[2];
    {
        const int qrow = rowbase + q0 + w * 16 + lr;
#pragma unroll
        for (int ks = 0; ks < 2; ks++) {
            short8 raw = *reinterpret_cast<const short8*>(
                &qkv[(size_t)qrow * QKVN_ + qoff + ks * 32 + lg * 8]);
            const u16* ru = reinterpret_cast<const u16*>(&raw);
            union { u16 u[8]; bf16x8 v; } q;
#pragma unroll
            for (int j = 0; j < 8; j++) q.u[j] = f2bf(bf2f(ru[j]) * 0.125f);
            qf[ks] = q.v;
        }
    }

    float mrow[4], lrow[4];
#pragma unroll
    for (int r = 0; r < 4; r++) { mrow[r] = -1e30f; lrow[r] = 0.f; }
    f32x4 acc_o[4] = {};

    const int sr = tid >> 3;          // 0..31 staging row
    const int sc = (tid & 7) * 8;     // 0..56 staging col
    const size_t kbase = (size_t)rowbase * QKVN_ + DIM_ + qoff;
    const size_t vbase = (size_t)rowbase * QKVN_ + 2 * DIM_ + qoff;

    for (int t = 0; t < N_ / 32; t++) {
        const int kv0 = t * 32;
        // stage K tile (row-major) and V tile (transposed)
        short8 k8 = *reinterpret_cast<const short8*>(&qkv[kbase + (size_t)(kv0 + sr) * QKVN_ + sc]);
        *reinterpret_cast<short8*>(&Ks[sr][sc]) = k8;
        short8 v8 = *reinterpret_cast<const short8*>(&qkv[vbase + (size_t)(kv0 + sr) * QKVN_ + sc]);
        const u16* vv = reinterpret_cast<const u16*>(&v8);
#pragma unroll
        for (int i = 0; i < 8; i++) VTs[sc + i][sr] = vv[i];
        __syncthreads();

        // S = Q K^T  (scaled)
        f32x4 sacc[2];
#pragma unroll
        for (int n = 0; n < 2; n++) {
            bf16x8 kf0 = *reinterpret_cast<const bf16x8*>(&Ks[n * 16 + lr][lg * 8]);
            bf16x8 kf1 = *reinterpret_cast<const bf16x8*>(&Ks[n * 16 + lr][32 + lg * 8]);
            f32x4 z = {0.f, 0.f, 0.f, 0.f};
            sacc[n] = __builtin_amdgcn_mfma_f32_16x16x32_bf16(qf[0], kf0, z, 0, 0, 0);
            sacc[n] = __builtin_amdgcn_mfma_f32_16x16x32_bf16(qf[1], kf1, sacc[n], 0, 0, 0);
        }

        // online softmax per q-row (rows lg*4+r, kv cols over lanes lr and n)
#pragma unroll
        for (int r = 0; r < 4; r++) {
            float s0 = sacc[0][r], s1 = sacc[1][r];
            float mx = fmaxf(s0, s1);
#pragma unroll
            for (int d = 1; d < 16; d <<= 1) mx = fmaxf(mx, __shfl_xor(mx, d));
            float mnew = fmaxf(mrow[r], mx);
            float fac  = __expf(mrow[r] - mnew);
            float p0 = __expf(s0 - mnew);
            float p1 = __expf(s1 - mnew);
            float ps = p0 + p1;
#pragma unroll
            for (int d = 1; d < 16; d <<= 1) ps += __shfl_xor(ps, d);
            lrow[r] = lrow[r] * fac + ps;
            mrow[r] = mnew;
#pragma unroll
            for (int n = 0; n < 4; n++) acc_o[n][r] *= fac;
            Ps[w][lg * 4 + r][lr]      = f2bf(p0);
            Ps[w][lg * 4 + r][16 + lr] = f2bf(p1);
        }

        // O += P V
        bf16x8 pf = *reinterpret_cast<const bf16x8*>(&Ps[w][lr][lg * 8]);
#pragma unroll
        for (int n = 0; n < 4; n++) {
            bf16x8 vf = *reinterpret_cast<const bf16x8*>(&VTs[n * 16 + lr][lg * 8]);
            acc_o[n] = __builtin_amdgcn_mfma_f32_16x16x32_bf16(pf, vf, acc_o[n], 0, 0, 0);
        }
        __syncthreads();
    }

    // normalize + store bf16 [row][h*64+d]
#pragma unroll
    for (int n = 0; n < 4; n++)
#pragma unroll
        for (int r = 0; r < 4; r++) {
            const int row = rowbase + q0 + w * 16 + lg * 4 + r;
            const int col = qoff + n * 16 + lr;
            out[(size_t)row * DIM_ + col] = f2bf(acc_o[n][r] * (1.f / lrow[r]));
        }
}

// ---------------- launcher ----------------
extern "C" void kernel_launch(void* const* d_in, const int* in_sizes, int n_in,
                              void* d_out, int out_size, void* d_ws, size_t ws_size,
                              hipStream_t stream) {
    const float* x     = (const float*)d_in[0];
    const float* w_qkv = (const float*)d_in[1];
    const float* w_out = (const float*)d_in[2];
    const float* b_out = (const float*)d_in[3];
    float* out = (float*)d_out;

    char* ws = (char*)d_ws;
    u16* xbf   = (u16*)(ws);                       // 8192*1024  bf16 = 16 MiB
    u16* wqkvT = (u16*)(ws + 16777216);            // 3072*1024  bf16 =  6 MiB
    u16* woutT = (u16*)(ws + 23068672);            // 1024*1024  bf16 =  2 MiB
    u16* qkv   = (u16*)(ws + 25165824);            // 8192*3072  bf16 = 48 MiB
    u16* attnO = (u16*)(ws + 75497472);            // 8192*1024  bf16 = 16 MiB

    cast_f32_bf16<<<2048, 256, 0, stream>>>(x, xbf, (BN_ * DIM_) / 4);
    transpose_cast<<<(DIM_ / 4) * QKVN_ / 256, 256, 0, stream>>>(w_qkv, wqkvT, DIM_, QKVN_);
    transpose_cast<<<(DIM_ / 4) * DIM_ / 256, 256, 0, stream>>>(w_out, woutT, DIM_, DIM_);

    gemm_bt<true><<<dim3(QKVN_ / 128, BN_ / 128), 256, 0, stream>>>(
        xbf, wqkvT, qkv, nullptr, BN_, QKVN_, DIM_);

    attn_kernel<<<dim3(N_ / 64, B_ * H_), 256, 0, stream>>>(qkv, attnO);

    gemm_bt<false><<<dim3(DIM_ / 128, BN_ / 128), 256, 0, stream>>>(
        attnO, woutT, out, b_out, BN_, DIM_, DIM_);
}

// Round 4
// 363.323 us; speedup vs baseline: 1.6828x; 1.6828x over previous
//
#include <hip/hip_runtime.h>
#include <stdint.h>

#define B_    4
#define N_    2048
#define DIM_  1024
#define H_    16
#define DH_   64
#define BN_   (B_ * N_)        // 8192 rows
#define QKVN_ (3 * H_ * DH_)   // 3072 qkv cols

typedef unsigned short u16;
typedef __attribute__((ext_vector_type(8))) __bf16 bf16x8;
typedef __attribute__((ext_vector_type(8))) short  short8;
typedef __attribute__((ext_vector_type(4))) float  f32x4;
typedef __attribute__((ext_vector_type(4))) u16    u16x4;

__device__ inline u16 f2bf(float f) {
    union { float f; uint32_t u; } v; v.f = f;
    uint32_t r = v.u + 0x7fffu + ((v.u >> 16) & 1u);   // RNE
    return (u16)(r >> 16);
}
__device__ inline float bf2f(u16 u) {
    union { uint32_t u; float f; } v; v.u = ((uint32_t)u) << 16;
    return v.f;
}

// ---------------- elementwise cast fp32 -> bf16 ----------------
__global__ __launch_bounds__(256) void cast_f32_bf16(const float* __restrict__ in,
                                                     u16* __restrict__ out, int n4) {
    int i = blockIdx.x * blockDim.x + threadIdx.x;
    int stride = gridDim.x * blockDim.x;
    for (; i < n4; i += stride) {
        float4 v = reinterpret_cast<const float4*>(in)[i];
        u16x4 o;
        o.x = f2bf(v.x); o.y = f2bf(v.y); o.z = f2bf(v.z); o.w = f2bf(v.w);
        reinterpret_cast<u16x4*>(out)[i] = o;
    }
}

// -------- cast + transpose: in[R][C] fp32 -> out[C][R] bf16 --------
__global__ __launch_bounds__(256) void transpose_cast(const float* __restrict__ in,
                                                      u16* __restrict__ out, int R, int C) {
    int gid = blockIdx.x * blockDim.x + threadIdx.x;
    int total = C * (R / 4);
    if (gid >= total) return;
    int n  = gid % C;
    int k4 = (gid / C) * 4;
    u16x4 o;
    o.x = f2bf(in[(size_t)(k4 + 0) * C + n]);
    o.y = f2bf(in[(size_t)(k4 + 1) * C + n]);
    o.z = f2bf(in[(size_t)(k4 + 2) * C + n]);
    o.w = f2bf(in[(size_t)(k4 + 3) * C + n]);
    *reinterpret_cast<u16x4*>(&out[(size_t)n * R + k4]) = o;
}

// ---------------- GEMM: C[M,N] = A[M,K] * BT[N,K]^T ----------------
template <bool BF16_OUT>
__global__ __launch_bounds__(256) void gemm_bt(const u16* __restrict__ A,
                                               const u16* __restrict__ BT,
                                               void* __restrict__ Cout,
                                               const float* __restrict__ bias,
                                               int M, int Nn, int K) {
    __shared__ u16 As[128][40];
    __shared__ u16 Bs[128][40];

    const int tid  = threadIdx.x;
    const int m0   = blockIdx.y * 128;
    const int n0   = blockIdx.x * 128;
    const int w    = tid >> 6;
    const int lane = tid & 63;
    const int lr   = lane & 15;
    const int lg   = lane >> 4;
    const int wm   = w >> 1;
    const int wn   = w & 1;

    f32x4 acc[4][4] = {};

    const int sr = tid >> 2;
    const int sc = (tid & 3) * 8;
    const u16* Aptr = A  + (size_t)(m0 + sr) * K + sc;
    const u16* Bptr = BT + (size_t)(n0 + sr) * K + sc;

    for (int kt = 0; kt < K; kt += 32) {
        *reinterpret_cast<short8*>(&As[sr][sc])      = *reinterpret_cast<const short8*>(Aptr + kt);
        *reinterpret_cast<short8*>(&As[sr + 64][sc]) = *reinterpret_cast<const short8*>(Aptr + (size_t)64 * K + kt);
        *reinterpret_cast<short8*>(&Bs[sr][sc])      = *reinterpret_cast<const short8*>(Bptr + kt);
        *reinterpret_cast<short8*>(&Bs[sr + 64][sc]) = *reinterpret_cast<const short8*>(Bptr + (size_t)64 * K + kt);
        __syncthreads();

        bf16x8 af[4], bfr[4];
#pragma unroll
        for (int m = 0; m < 4; m++)
            af[m] = *reinterpret_cast<const bf16x8*>(&As[wm * 64 + m * 16 + lr][lg * 8]);
#pragma unroll
        for (int n = 0; n < 4; n++)
            bfr[n] = *reinterpret_cast<const bf16x8*>(&Bs[wn * 64 + n * 16 + lr][lg * 8]);
#pragma unroll
        for (int m = 0; m < 4; m++)
#pragma unroll
            for (int n = 0; n < 4; n++)
                acc[m][n] = __builtin_amdgcn_mfma_f32_16x16x32_bf16(af[m], bfr[n], acc[m][n], 0, 0, 0);
        __syncthreads();
    }

#pragma unroll
    for (int m = 0; m < 4; m++)
#pragma unroll
        for (int n = 0; n < 4; n++) {
            const int row = m0 + wm * 64 + m * 16 + lg * 4;
            const int col = n0 + wn * 64 + n * 16 + lr;
#pragma unroll
            for (int r = 0; r < 4; r++) {
                if (BF16_OUT) {
                    ((u16*)Cout)[(size_t)(row + r) * Nn + col] = f2bf(acc[m][n][r]);
                } else {
                    ((float*)Cout)[(size_t)(row + r) * Nn + col] = acc[m][n][r] + bias[col];
                }
            }
        }
}

// ---------------- flash attention v3 ----------------
// grid: (N/64, B*H). 256 threads = 4 waves, each wave owns 16 q-rows.
// Swapped QK^T: S^T = mfma(K, Q); lane (lr,lg) holds S[kv=n*16+lg*4+r][q=lr]
// -> row softmax = 2 shfl_xor. P via per-wave LDS (b64 write / b128 read).
// V staged TRANSPOSED at global->LDS time into VT32[d][kv/2] (u32 packs the
// kv-pair), XOR column swizzle ((kv/2) ^ (((d>>2)&7)<<2)) -> conflict-free
// u32 writes AND contiguous 16B-aligned b128 B-fragment reads (GEMM-proven
// pattern). No inline asm, no addrspace casts.
__global__ __launch_bounds__(256) void attn_kernel(const u16* __restrict__ qkv,
                                                   u16* __restrict__ out) {
    __shared__ __align__(16) u16      Ks[2][64][40];     // [d-half][kv][32d+pad] 10 KB
    __shared__ __align__(16) uint32_t VT32[64 * 36];     // [d][kv-pair] pitch 36  9 KB
    __shared__ __align__(16) u16      Ps[4][16][72];     // per-wave P [q][kv]     9 KB

    const int tid  = threadIdx.x;
    const int w    = tid >> 6;
    const int lane = tid & 63;
    const int lr   = lane & 15;
    const int lg   = lane >> 4;

    const int bh = blockIdx.y;
    const int b  = bh >> 4;
    const int h  = bh & 15;
    const int rowbase = b * N_;
    const int q0 = blockIdx.x * 64;
    const int qoff = h * DH_;

    // Q fragments (used as B-operand), scaled by DH^-0.5 = 0.125
    bf16x8 qf[2];
    {
        const int qrow = rowbase + q0 + w * 16 + lr;
#pragma unroll
        for (int ks = 0; ks < 2; ks++) {
            short8 raw = *reinterpret_cast<const short8*>(
                &qkv[(size_t)qrow * QKVN_ + qoff + ks * 32 + lg * 8]);
            const u16* ru = reinterpret_cast<const u16*>(&raw);
            union { u16 u[8]; bf16x8 v; } q;
#pragma unroll
            for (int j = 0; j < 8; j++) q.u[j] = f2bf(bf2f(ru[j]) * 0.125f);
            qf[ks] = q.v;
        }
    }

    float mrun = -3e38f, lrun = 0.f;
    f32x4 acc_o[4] = {};

    const u16* kg = qkv + (size_t)rowbase * QKVN_ + DIM_ + qoff;
    const u16* vg = qkv + (size_t)rowbase * QKVN_ + 2 * DIM_ + qoff;

    // --- staging maps ---
    // K: thread -> (kv = tid>>2, d-chunk i*32 + (tid&3)*8), dest Ks[i][kv][(tid&3)*8]
    const int kr = tid >> 2;
    const int kc = (tid & 3) * 8;
    const size_t koff0 = (size_t)kr * QKVN_ + kc;
    // V: thread -> kv-pair (2*(tid>>3), +1), d-range (tid&7)*8 .. +7
    const int vp  = tid >> 3;            // kv-pair index 0..31
    const int vsc = (tid & 7) * 8;       // d start
    const size_t voff0 = (size_t)(vp * 2) * QKVN_ + vsc;
    const size_t voff1 = voff0 + QKVN_;

    short8 kst[2], vst[2];
    kst[0] = *reinterpret_cast<const short8*>(kg + koff0);
    kst[1] = *reinterpret_cast<const short8*>(kg + koff0 + 32);
    vst[0] = *reinterpret_cast<const short8*>(vg + voff0);
    vst[1] = *reinterpret_cast<const short8*>(vg + voff1);

    *reinterpret_cast<short8*>(&Ks[0][kr][kc]) = kst[0];
    *reinterpret_cast<short8*>(&Ks[1][kr][kc]) = kst[1];
    {
        const u16* v0 = reinterpret_cast<const u16*>(&vst[0]);
        const u16* v1 = reinterpret_cast<const u16*>(&vst[1]);
#pragma unroll
        for (int i = 0; i < 8; i++) {
            const int d = vsc + i;
            const int col = vp ^ (((d >> 2) & 7) << 2);
            VT32[d * 36 + col] = (uint32_t)v0[i] | ((uint32_t)v1[i] << 16);
        }
    }
    __syncthreads();

    for (int t = 0; t < N_ / 64; t++) {
        // async-STAGE split: issue next tile's global loads before compute
        if (t + 1 < N_ / 64) {
            const u16* kg2 = kg + (size_t)(t + 1) * 64 * QKVN_;
            const u16* vg2 = vg + (size_t)(t + 1) * 64 * QKVN_;
            kst[0] = *reinterpret_cast<const short8*>(kg2 + koff0);
            kst[1] = *reinterpret_cast<const short8*>(kg2 + koff0 + 32);
            vst[0] = *reinterpret_cast<const short8*>(vg2 + voff0);
            vst[1] = *reinterpret_cast<const short8*>(vg2 + voff1);
        }

        // S^T = K Q^T : s[n][r] = S[kv=n*16+lg*4+r][q=lr]
        f32x4 s[4];
#pragma unroll
        for (int n = 0; n < 4; n++) {
            bf16x8 k0 = *reinterpret_cast<const bf16x8*>(&Ks[0][n * 16 + lr][lg * 8]);
            bf16x8 k1 = *reinterpret_cast<const bf16x8*>(&Ks[1][n * 16 + lr][lg * 8]);
            f32x4 z = {0.f, 0.f, 0.f, 0.f};
            s[n] = __builtin_amdgcn_mfma_f32_16x16x32_bf16(k0, qf[0], z, 0, 0, 0);
            s[n] = __builtin_amdgcn_mfma_f32_16x16x32_bf16(k1, qf[1], s[n], 0, 0, 0);
        }

        // online softmax for q=lr (4 lanes lg share the row: 2 shfl_xor each)
        float tmax = fmaxf(fmaxf(s[0][0], s[0][1]), fmaxf(s[0][2], s[0][3]));
#pragma unroll
        for (int n = 1; n < 4; n++)
            tmax = fmaxf(tmax, fmaxf(fmaxf(s[n][0], s[n][1]), fmaxf(s[n][2], s[n][3])));
        tmax = fmaxf(tmax, __shfl_xor(tmax, 16));
        tmax = fmaxf(tmax, __shfl_xor(tmax, 32));
        float mnew = fmaxf(mrun, tmax);
        float fac = __expf(mrun - mnew);
        mrun = mnew;
        float psum = 0.f;
#pragma unroll
        for (int n = 0; n < 4; n++) {
            float p0 = __expf(s[n][0] - mnew);
            float p1 = __expf(s[n][1] - mnew);
            float p2 = __expf(s[n][2] - mnew);
            float p3 = __expf(s[n][3] - mnew);
            psum += (p0 + p1) + (p2 + p3);
            u16x4 pw;
            pw.x = f2bf(p0); pw.y = f2bf(p1); pw.z = f2bf(p2); pw.w = f2bf(p3);
            *reinterpret_cast<u16x4*>(&Ps[w][lr][n * 16 + lg * 4]) = pw;
        }
        psum += __shfl_xor(psum, 16);
        psum += __shfl_xor(psum, 32);
        lrun = lrun * fac + psum;

        // rescale O (per-row factor lives at lane lr==row; gather it)
        float facq[4];
#pragma unroll
        for (int r = 0; r < 4; r++) facq[r] = __shfl(fac, (lane & 48) | (lg * 4 + r));
#pragma unroll
        for (int n = 0; n < 4; n++)
#pragma unroll
            for (int r = 0; r < 4; r++) acc_o[n][r] *= facq[r];

        // O += P V ; P as A-operand, V as B-operand from swizzled VT32
#pragma unroll
        for (int c = 0; c < 2; c++) {
            bf16x8 pa = *reinterpret_cast<const bf16x8*>(&Ps[w][lr][c * 32 + lg * 8]);
#pragma unroll
            for (int n = 0; n < 4; n++) {
                const int d = n * 16 + lr;
                const int bc = (c * 16 + lg * 4) ^ (((d >> 2) & 7) << 2);
                bf16x8 vf = *reinterpret_cast<const bf16x8*>(&VT32[d * 36 + bc]);
                acc_o[n] = __builtin_amdgcn_mfma_f32_16x16x32_bf16(pa, vf, acc_o[n], 0, 0, 0);
            }
        }

        __syncthreads();
        if (t + 1 < N_ / 64) {
            *reinterpret_cast<short8*>(&Ks[0][kr][kc]) = kst[0];
            *reinterpret_cast<short8*>(&Ks[1][kr][kc]) = kst[1];
            const u16* v0 = reinterpret_cast<const u16*>(&vst[0]);
            const u16* v1 = reinterpret_cast<const u16*>(&vst[1]);
#pragma unroll
            for (int i = 0; i < 8; i++) {
                const int d = vsc + i;
                const int col = vp ^ (((d >> 2) & 7) << 2);
                VT32[d * 36 + col] = (uint32_t)v0[i] | ((uint32_t)v1[i] << 16);
            }
        }
        __syncthreads();
    }

    float linv = 1.f / lrun;
    float lq[4];
#pragma unroll
    for (int r = 0; r < 4; r++) lq[r] = __shfl(linv, (lane & 48) | (lg * 4 + r));
#pragma unroll
    for (int n = 0; n < 4; n++)
#pragma unroll
        for (int r = 0; r < 4; r++) {
            const int row = rowbase + q0 + w * 16 + lg * 4 + r;
            const int col = qoff + n * 16 + lr;
            out[(size_t)row * DIM_ + col] = f2bf(acc_o[n][r] * lq[r]);
        }
}

// ---------------- launcher ----------------
extern "C" void kernel_launch(void* const* d_in, const int* in_sizes, int n_in,
                              void* d_out, int out_size, void* d_ws, size_t ws_size,
                              hipStream_t stream) {
    const float* x     = (const float*)d_in[0];
    const float* w_qkv = (const float*)d_in[1];
    const float* w_out = (const float*)d_in[2];
    const float* b_out = (const float*)d_in[3];
    float* out = (float*)d_out;

    char* ws = (char*)d_ws;
    u16* xbf   = (u16*)(ws);                       // 8192*1024  bf16 = 16 MiB
    u16* wqkvT = (u16*)(ws + 16777216);            // 3072*1024  bf16 =  6 MiB
    u16* woutT = (u16*)(ws + 23068672);            // 1024*1024  bf16 =  2 MiB
    u16* qkv   = (u16*)(ws + 25165824);            // 8192*3072  bf16 = 48 MiB
    u16* attnO = (u16*)(ws + 75497472);            // 8192*1024  bf16 = 16 MiB

    cast_f32_bf16<<<2048, 256, 0, stream>>>(x, xbf, (BN_ * DIM_) / 4);
    transpose_cast<<<(DIM_ / 4) * QKVN_ / 256, 256, 0, stream>>>(w_qkv, wqkvT, DIM_, QKVN_);
    transpose_cast<<<(DIM_ / 4) * DIM_ / 256, 256, 0, stream>>>(w_out, woutT, DIM_, DIM_);

    gemm_bt<true><<<dim3(QKVN_ / 128, BN_ / 128), 256, 0, stream>>>(
        xbf, wqkvT, qkv, nullptr, BN_, QKVN_, DIM_);

    attn_kernel<<<dim3(N_ / 64, B_ * H_), 256, 0, stream>>>(qkv, attnO);

    gemm_bt<false><<<dim3(DIM_ / 128, BN_ / 128), 256, 0, stream>>>(
        attnO, woutT, out, b_out, BN_, DIM_, DIM_);
}

// Round 5
// 351.793 us; speedup vs baseline: 1.7380x; 1.0328x over previous
//
#include <hip/hip_runtime.h>
#include <stdint.h>

#define B_    4
#define N_    2048
#define DIM_  1024
#define H_    16
#define DH_   64
#define BN_   (B_ * N_)        // 8192 rows
#define QKVN_ (3 * H_ * DH_)   // 3072 qkv cols

#define AS1_ __attribute__((address_space(1)))
#define AS3_ __attribute__((address_space(3)))

typedef unsigned short u16;
typedef __attribute__((ext_vector_type(8))) __bf16 bf16x8;
typedef __attribute__((ext_vector_type(8))) short  short8;
typedef __attribute__((ext_vector_type(4))) float  f32x4;
typedef __attribute__((ext_vector_type(4))) u16    u16x4;

__device__ inline u16 f2bf(float f) {            // native RNE cast (v_cvt_pk-able)
    union { __bf16 b; u16 u; } v; v.b = (__bf16)f; return v.u;
}
__device__ inline float bf2f(u16 u) {
    union { uint32_t u; float f; } v; v.u = ((uint32_t)u) << 16;
    return v.f;
}

// ---------------- elementwise cast fp32 -> bf16 ----------------
__global__ __launch_bounds__(256) void cast_f32_bf16(const float* __restrict__ in,
                                                     u16* __restrict__ out, int n4) {
    int i = blockIdx.x * blockDim.x + threadIdx.x;
    int stride = gridDim.x * blockDim.x;
    for (; i < n4; i += stride) {
        float4 v = reinterpret_cast<const float4*>(in)[i];
        u16x4 o;
        o.x = f2bf(v.x); o.y = f2bf(v.y); o.z = f2bf(v.z); o.w = f2bf(v.w);
        reinterpret_cast<u16x4*>(out)[i] = o;
    }
}

// -------- cast + transpose: in[R][C] fp32 -> out[C][R] bf16 --------
__global__ __launch_bounds__(256) void transpose_cast(const float* __restrict__ in,
                                                      u16* __restrict__ out, int R, int C) {
    int gid = blockIdx.x * blockDim.x + threadIdx.x;
    int total = C * (R / 4);
    if (gid >= total) return;
    int n  = gid % C;
    int k4 = (gid / C) * 4;
    u16x4 o;
    o.x = f2bf(in[(size_t)(k4 + 0) * C + n]);
    o.y = f2bf(in[(size_t)(k4 + 1) * C + n]);
    o.z = f2bf(in[(size_t)(k4 + 2) * C + n]);
    o.w = f2bf(in[(size_t)(k4 + 3) * C + n]);
    *reinterpret_cast<u16x4*>(&out[(size_t)n * R + k4]) = o;
}

// ---------------- GEMM: C[M,N] = A[M,K] * BT[N,K]^T  (m97 structure) --------
// 128x128 tile, BK=32, 4 waves 2x2, 4x4 16x16x32 frags. Staging via
// global_load_lds width=16: LDS dest linear (tid*16B = wave base + lane*16),
// unpadded [128][32] LDS (64B rows).
template <bool BF16_OUT>
__global__ __launch_bounds__(256) void gemm_bt(const u16* __restrict__ A,
                                               const u16* __restrict__ BT,
                                               void* __restrict__ Cout,
                                               const float* __restrict__ bias,
                                               int M, int Nn, int K) {
    __shared__ __align__(16) u16 AsF[128 * 32];   // 8 KB
    __shared__ __align__(16) u16 BsF[128 * 32];   // 8 KB

    const int tid  = threadIdx.x;
    const int m0   = blockIdx.y * 128;
    const int n0   = blockIdx.x * 128;
    const int w    = tid >> 6;
    const int lane = tid & 63;
    const int lr   = lane & 15;
    const int lg   = lane >> 4;
    const int wm   = w >> 1;
    const int wn   = w & 1;

    f32x4 acc[4][4] = {};

    const int sr = tid >> 2;            // row 0..63 (+64 second half)
    const int sc = (tid & 3) * 8;       // col in u16
    const u16* Aptr = A  + (size_t)(m0 + sr) * K + sc;
    const u16* Bptr = BT + (size_t)(n0 + sr) * K + sc;
    const int ldsb = w * 512;           // wave-uniform LDS base (elements)

    for (int kt = 0; kt < K; kt += 32) {
        __builtin_amdgcn_global_load_lds((const AS1_ void*)(Aptr + kt),
                                         (AS3_ void*)&AsF[ldsb], 16, 0, 0);
        __builtin_amdgcn_global_load_lds((const AS1_ void*)(Aptr + (size_t)64 * K + kt),
                                         (AS3_ void*)&AsF[2048 + ldsb], 16, 0, 0);
        __builtin_amdgcn_global_load_lds((const AS1_ void*)(Bptr + kt),
                                         (AS3_ void*)&BsF[ldsb], 16, 0, 0);
        __builtin_amdgcn_global_load_lds((const AS1_ void*)(Bptr + (size_t)64 * K + kt),
                                         (AS3_ void*)&BsF[2048 + ldsb], 16, 0, 0);
        __syncthreads();   // drains vmcnt(0) -> LDS tiles ready

        bf16x8 af[4], bfr[4];
#pragma unroll
        for (int m = 0; m < 4; m++)
            af[m] = *reinterpret_cast<const bf16x8*>(&AsF[(wm * 64 + m * 16 + lr) * 32 + lg * 8]);
#pragma unroll
        for (int n = 0; n < 4; n++)
            bfr[n] = *reinterpret_cast<const bf16x8*>(&BsF[(wn * 64 + n * 16 + lr) * 32 + lg * 8]);
#pragma unroll
        for (int m = 0; m < 4; m++)
#pragma unroll
            for (int n = 0; n < 4; n++)
                acc[m][n] = __builtin_amdgcn_mfma_f32_16x16x32_bf16(af[m], bfr[n], acc[m][n], 0, 0, 0);
        __syncthreads();
    }

#pragma unroll
    for (int m = 0; m < 4; m++)
#pragma unroll
        for (int n = 0; n < 4; n++) {
            const int row = m0 + wm * 64 + m * 16 + lg * 4;
            const int col = n0 + wn * 64 + n * 16 + lr;
#pragma unroll
            for (int r = 0; r < 4; r++) {
                if (BF16_OUT) {
                    ((u16*)Cout)[(size_t)(row + r) * Nn + col] = f2bf(acc[m][n][r]);
                } else {
                    ((float*)Cout)[(size_t)(row + r) * Nn + col] = acc[m][n][r] + bias[col];
                }
            }
        }
}

// ---------------- flash attention v4 ----------------
// Structure identical to passing v3; VALU diet: native bf16 casts (cvt_pk),
// exp2-domain softmax (log2e folded into Q scale), T13 defer-max (THR=8),
// hoisted V-read swizzle offsets.
__global__ __launch_bounds__(256) void attn_kernel(const u16* __restrict__ qkv,
                                                   u16* __restrict__ out) {
    __shared__ __align__(16) u16      Ks[2][64][40];     // [d-half][kv][32d+pad] 10 KB
    __shared__ __align__(16) uint32_t VT32[64 * 36];     // [d][kv-pair] pitch 36  9 KB
    __shared__ __align__(16) u16      Ps[4][16][72];     // per-wave P [q][kv]     9 KB

    const int tid  = threadIdx.x;
    const int w    = tid >> 6;
    const int lane = tid & 63;
    const int lr   = lane & 15;
    const int lg   = lane >> 4;

    const int bh = blockIdx.y;
    const int b  = bh >> 4;
    const int h  = bh & 15;
    const int rowbase = b * N_;
    const int q0 = blockIdx.x * 64;
    const int qoff = h * DH_;

    // Q fragments (B-operand), scaled by DH^-0.5 * log2(e) -> exp2-domain softmax
    bf16x8 qf[2];
    {
        const float qscale = 0.125f * 1.4426950408889634f;
        const int qrow = rowbase + q0 + w * 16 + lr;
#pragma unroll
        for (int ks = 0; ks < 2; ks++) {
            short8 raw = *reinterpret_cast<const short8*>(
                &qkv[(size_t)qrow * QKVN_ + qoff + ks * 32 + lg * 8]);
            const u16* ru = reinterpret_cast<const u16*>(&raw);
            union { u16 u[8]; bf16x8 v; } q;
#pragma unroll
            for (int j = 0; j < 8; j++) q.u[j] = f2bf(bf2f(ru[j]) * qscale);
            qf[ks] = q.v;
        }
    }

    float mrun = -3e38f, lrun = 0.f;
    f32x4 acc_o[4] = {};

    const u16* kg = qkv + (size_t)rowbase * QKVN_ + DIM_ + qoff;
    const u16* vg = qkv + (size_t)rowbase * QKVN_ + 2 * DIM_ + qoff;

    // --- staging maps ---
    const int kr = tid >> 2;
    const int kc = (tid & 3) * 8;
    const size_t koff0 = (size_t)kr * QKVN_ + kc;
    const int vp  = tid >> 3;            // kv-pair index 0..31
    const int vsc = (tid & 7) * 8;       // d start
    const size_t voff0 = (size_t)(vp * 2) * QKVN_ + vsc;
    const size_t voff1 = voff0 + QKVN_;

    // hoisted V-read swizzled column offsets: vb_off[c][n] for d = n*16+lr
    int vb_off[2][4];
#pragma unroll
    for (int c = 0; c < 2; c++)
#pragma unroll
        for (int n = 0; n < 4; n++) {
            const int d = n * 16 + lr;
            vb_off[c][n] = d * 36 + ((c * 16 + lg * 4) ^ (((d >> 2) & 7) << 2));
        }

    short8 kst[2], vst[2];
    kst[0] = *reinterpret_cast<const short8*>(kg + koff0);
    kst[1] = *reinterpret_cast<const short8*>(kg + koff0 + 32);
    vst[0] = *reinterpret_cast<const short8*>(vg + voff0);
    vst[1] = *reinterpret_cast<const short8*>(vg + voff1);

    *reinterpret_cast<short8*>(&Ks[0][kr][kc]) = kst[0];
    *reinterpret_cast<short8*>(&Ks[1][kr][kc]) = kst[1];
    {
        const u16* v0 = reinterpret_cast<const u16*>(&vst[0]);
        const u16* v1 = reinterpret_cast<const u16*>(&vst[1]);
#pragma unroll
        for (int i = 0; i < 8; i++) {
            const int d = vsc + i;
            const int col = vp ^ (((d >> 2) & 7) << 2);
            VT32[d * 36 + col] = (uint32_t)v0[i] | ((uint32_t)v1[i] << 16);
        }
    }
    __syncthreads();

    for (int t = 0; t < N_ / 64; t++) {
        // async-STAGE split: issue next tile's global loads before compute
        if (t + 1 < N_ / 64) {
            const u16* kg2 = kg + (size_t)(t + 1) * 64 * QKVN_;
            const u16* vg2 = vg + (size_t)(t + 1) * 64 * QKVN_;
            kst[0] = *reinterpret_cast<const short8*>(kg2 + koff0);
            kst[1] = *reinterpret_cast<const short8*>(kg2 + koff0 + 32);
            vst[0] = *reinterpret_cast<const short8*>(vg2 + voff0);
            vst[1] = *reinterpret_cast<const short8*>(vg2 + voff1);
        }

        // S^T = K Q^T : s[n][r] = S[kv=n*16+lg*4+r][q=lr]  (log2 domain)
        f32x4 s[4];
#pragma unroll
        for (int n = 0; n < 4; n++) {
            bf16x8 k0 = *reinterpret_cast<const bf16x8*>(&Ks[0][n * 16 + lr][lg * 8]);
            bf16x8 k1 = *reinterpret_cast<const bf16x8*>(&Ks[1][n * 16 + lr][lg * 8]);
            f32x4 z = {0.f, 0.f, 0.f, 0.f};
            s[n] = __builtin_amdgcn_mfma_f32_16x16x32_bf16(k0, qf[0], z, 0, 0, 0);
            s[n] = __builtin_amdgcn_mfma_f32_16x16x32_bf16(k1, qf[1], s[n], 0, 0, 0);
        }

        // online softmax (exp2 domain) with defer-max (THR=8)
        float tmax = fmaxf(fmaxf(s[0][0], s[0][1]), fmaxf(s[0][2], s[0][3]));
#pragma unroll
        for (int n = 1; n < 4; n++)
            tmax = fmaxf(tmax, fmaxf(fmaxf(s[n][0], s[n][1]), fmaxf(s[n][2], s[n][3])));
        tmax = fmaxf(tmax, __shfl_xor(tmax, 16));
        tmax = fmaxf(tmax, __shfl_xor(tmax, 32));

        if (!__all(tmax - mrun <= 8.f)) {
            float mnew = fmaxf(mrun, tmax);
            float fac  = exp2f(mrun - mnew);
            mrun = mnew;
            lrun *= fac;
            float facq[4];
#pragma unroll
            for (int r = 0; r < 4; r++) facq[r] = __shfl(fac, (lane & 48) | (lg * 4 + r));
#pragma unroll
            for (int n = 0; n < 4; n++)
#pragma unroll
                for (int r = 0; r < 4; r++) acc_o[n][r] *= facq[r];
        }

        float psum = 0.f;
#pragma unroll
        for (int n = 0; n < 4; n++) {
            float p0 = exp2f(s[n][0] - mrun);
            float p1 = exp2f(s[n][1] - mrun);
            float p2 = exp2f(s[n][2] - mrun);
            float p3 = exp2f(s[n][3] - mrun);
            psum += (p0 + p1) + (p2 + p3);
            u16x4 pw;
            pw.x = f2bf(p0); pw.y = f2bf(p1); pw.z = f2bf(p2); pw.w = f2bf(p3);
            *reinterpret_cast<u16x4*>(&Ps[w][lr][n * 16 + lg * 4]) = pw;
        }
        psum += __shfl_xor(psum, 16);
        psum += __shfl_xor(psum, 32);
        lrun += psum;

        // O += P V ; P as A-operand, V as B-operand from swizzled VT32
#pragma unroll
        for (int c = 0; c < 2; c++) {
            bf16x8 pa = *reinterpret_cast<const bf16x8*>(&Ps[w][lr][c * 32 + lg * 8]);
#pragma unroll
            for (int n = 0; n < 4; n++) {
                bf16x8 vf = *reinterpret_cast<const bf16x8*>(&VT32[vb_off[c][n]]);
                acc_o[n] = __builtin_amdgcn_mfma_f32_16x16x32_bf16(pa, vf, acc_o[n], 0, 0, 0);
            }
        }

        __syncthreads();
        if (t + 1 < N_ / 64) {
            *reinterpret_cast<short8*>(&Ks[0][kr][kc]) = kst[0];
            *reinterpret_cast<short8*>(&Ks[1][kr][kc]) = kst[1];
            const u16* v0 = reinterpret_cast<const u16*>(&vst[0]);
            const u16* v1 = reinterpret_cast<const u16*>(&vst[1]);
#pragma unroll
            for (int i = 0; i < 8; i++) {
                const int d = vsc + i;
                const int col = vp ^ (((d >> 2) & 7) << 2);
                VT32[d * 36 + col] = (uint32_t)v0[i] | ((uint32_t)v1[i] << 16);
            }
        }
        __syncthreads();
    }

    float linv = 1.f / lrun;
    float lq[4];
#pragma unroll
    for (int r = 0; r < 4; r++) lq[r] = __shfl(linv, (lane & 48) | (lg * 4 + r));
#pragma unroll
    for (int n = 0; n < 4; n++)
#pragma unroll
        for (int r = 0; r < 4; r++) {
            const int row = rowbase + q0 + w * 16 + lg * 4 + r;
            const int col = qoff + n * 16 + lr;
            out[(size_t)row * DIM_ + col] = f2bf(acc_o[n][r] * lq[r]);
        }
}

// ---------------- launcher ----------------
extern "C" void kernel_launch(void* const* d_in, const int* in_sizes, int n_in,
                              void* d_out, int out_size, void* d_ws, size_t ws_size,
                              hipStream_t stream) {
    const float* x     = (const float*)d_in[0];
    const float* w_qkv = (const float*)d_in[1];
    const float* w_out = (const float*)d_in[2];
    const float* b_out = (const float*)d_in[3];
    float* out = (float*)d_out;

    char* ws = (char*)d_ws;
    u16* xbf   = (u16*)(ws);                       // 8192*1024  bf16 = 16 MiB
    u16* wqkvT = (u16*)(ws + 16777216);            // 3072*1024  bf16 =  6 MiB
    u16* woutT = (u16*)(ws + 23068672);            // 1024*1024  bf16 =  2 MiB
    u16* qkv   = (u16*)(ws + 25165824);            // 8192*3072  bf16 = 48 MiB
    u16* attnO = (u16*)(ws + 75497472);            // 8192*1024  bf16 = 16 MiB

    cast_f32_bf16<<<2048, 256, 0, stream>>>(x, xbf, (BN_ * DIM_) / 4);
    transpose_cast<<<(DIM_ / 4) * QKVN_ / 256, 256, 0, stream>>>(w_qkv, wqkvT, DIM_, QKVN_);
    transpose_cast<<<(DIM_ / 4) * DIM_ / 256, 256, 0, stream>>>(w_out, woutT, DIM_, DIM_);

    gemm_bt<true><<<dim3(QKVN_ / 128, BN_ / 128), 256, 0, stream>>>(
        xbf, wqkvT, qkv, nullptr, BN_, QKVN_, DIM_);

    attn_kernel<<<dim3(N_ / 64, B_ * H_), 256, 0, stream>>>(qkv, attnO);

    gemm_bt<false><<<dim3(DIM_ / 128, BN_ / 128), 256, 0, stream>>>(
        attnO, woutT, out, b_out, BN_, DIM_, DIM_);
}

// Round 6
// 346.683 us; speedup vs baseline: 1.7636x; 1.0147x over previous
//
#include <hip/hip_runtime.h>
#include <stdint.h>

#define B_    4
#define N_    2048
#define DIM_  1024
#define H_    16
#define DH_   64
#define BN_   (B_ * N_)        // 8192 rows
#define QKVN_ (3 * H_ * DH_)   // 3072 qkv cols

#define AS1_ __attribute__((address_space(1)))
#define AS3_ __attribute__((address_space(3)))

typedef unsigned short u16;
typedef __attribute__((ext_vector_type(8)))  __bf16 bf16x8;
typedef __attribute__((ext_vector_type(8)))  short  short8;
typedef __attribute__((ext_vector_type(4)))  float  f32x4;
typedef __attribute__((ext_vector_type(16))) float  f32x16;
typedef __attribute__((ext_vector_type(4)))  u16    u16x4;

__device__ inline u16 f2bf(float f) {            // native RNE cast (cvt_pk-able)
    union { __bf16 b; u16 u; } v; v.b = (__bf16)f; return v.u;
}
__device__ inline float bf2f(u16 u) {
    union { uint32_t u; float f; } v; v.u = ((uint32_t)u) << 16;
    return v.f;
}

// ---------------- elementwise cast fp32 -> bf16 ----------------
__global__ __launch_bounds__(256) void cast_f32_bf16(const float* __restrict__ in,
                                                     u16* __restrict__ out, int n4) {
    int i = blockIdx.x * blockDim.x + threadIdx.x;
    int stride = gridDim.x * blockDim.x;
    for (; i < n4; i += stride) {
        float4 v = reinterpret_cast<const float4*>(in)[i];
        u16x4 o;
        o.x = f2bf(v.x); o.y = f2bf(v.y); o.z = f2bf(v.z); o.w = f2bf(v.w);
        reinterpret_cast<u16x4*>(out)[i] = o;
    }
}

// -------- cast + transpose: in[R][C] fp32 -> out[C][R] bf16 --------
__global__ __launch_bounds__(256) void transpose_cast(const float* __restrict__ in,
                                                      u16* __restrict__ out, int R, int C) {
    int gid = blockIdx.x * blockDim.x + threadIdx.x;
    int total = C * (R / 4);
    if (gid >= total) return;
    int n  = gid % C;
    int k4 = (gid / C) * 4;
    u16x4 o;
    o.x = f2bf(in[(size_t)(k4 + 0) * C + n]);
    o.y = f2bf(in[(size_t)(k4 + 1) * C + n]);
    o.z = f2bf(in[(size_t)(k4 + 2) * C + n]);
    o.w = f2bf(in[(size_t)(k4 + 3) * C + n]);
    *reinterpret_cast<u16x4*>(&out[(size_t)n * R + k4]) = o;
}

// ---------------- GEMM: C[M,N] = A[M,K] * BT[N,K]^T  (m97 structure) --------
template <bool BF16_OUT>
__global__ __launch_bounds__(256) void gemm_bt(const u16* __restrict__ A,
                                               const u16* __restrict__ BT,
                                               void* __restrict__ Cout,
                                               const float* __restrict__ bias,
                                               int M, int Nn, int K) {
    __shared__ __align__(16) u16 AsF[128 * 32];   // 8 KB
    __shared__ __align__(16) u16 BsF[128 * 32];   // 8 KB

    const int tid  = threadIdx.x;
    const int m0   = blockIdx.y * 128;
    const int n0   = blockIdx.x * 128;
    const int w    = tid >> 6;
    const int lane = tid & 63;
    const int lr   = lane & 15;
    const int lg   = lane >> 4;
    const int wm   = w >> 1;
    const int wn   = w & 1;

    f32x4 acc[4][4] = {};

    const int sr = tid >> 2;
    const int sc = (tid & 3) * 8;
    const u16* Aptr = A  + (size_t)(m0 + sr) * K + sc;
    const u16* Bptr = BT + (size_t)(n0 + sr) * K + sc;
    const int ldsb = w * 512;

    for (int kt = 0; kt < K; kt += 32) {
        __builtin_amdgcn_global_load_lds((const AS1_ void*)(Aptr + kt),
                                         (AS3_ void*)&AsF[ldsb], 16, 0, 0);
        __builtin_amdgcn_global_load_lds((const AS1_ void*)(Aptr + (size_t)64 * K + kt),
                                         (AS3_ void*)&AsF[2048 + ldsb], 16, 0, 0);
        __builtin_amdgcn_global_load_lds((const AS1_ void*)(Bptr + kt),
                                         (AS3_ void*)&BsF[ldsb], 16, 0, 0);
        __builtin_amdgcn_global_load_lds((const AS1_ void*)(Bptr + (size_t)64 * K + kt),
                                         (AS3_ void*)&BsF[2048 + ldsb], 16, 0, 0);
        __syncthreads();

        bf16x8 af[4], bfr[4];
#pragma unroll
        for (int m = 0; m < 4; m++)
            af[m] = *reinterpret_cast<const bf16x8*>(&AsF[(wm * 64 + m * 16 + lr) * 32 + lg * 8]);
#pragma unroll
        for (int n = 0; n < 4; n++)
            bfr[n] = *reinterpret_cast<const bf16x8*>(&BsF[(wn * 64 + n * 16 + lr) * 32 + lg * 8]);
#pragma unroll
        for (int m = 0; m < 4; m++)
#pragma unroll
            for (int n = 0; n < 4; n++)
                acc[m][n] = __builtin_amdgcn_mfma_f32_16x16x32_bf16(af[m], bfr[n], acc[m][n], 0, 0, 0);
        __syncthreads();
    }

#pragma unroll
    for (int m = 0; m < 4; m++)
#pragma unroll
        for (int n = 0; n < 4; n++) {
            const int row = m0 + wm * 64 + m * 16 + lg * 4;
            const int col = n0 + wn * 64 + n * 16 + lr;
#pragma unroll
            for (int r = 0; r < 4; r++) {
                if (BF16_OUT) {
                    ((u16*)Cout)[(size_t)(row + r) * Nn + col] = f2bf(acc[m][n][r]);
                } else {
                    ((float*)Cout)[(size_t)(row + r) * Nn + col] = acc[m][n][r] + bias[col];
                }
            }
        }
}

// ---------------- flash attention v5: per-lane-q 32x32 structure ----------------
// grid: (N/128, B*H). 256 thr = 4 waves, each wave owns 32 q-rows. KVBLK=64.
// QK^T via mfma_32x32x16: A=K rows (kv), B=Q cols (q=lane&31) -> S^T per-lane
// column: m/l/fac are PER-LANE SCALARS (no gathers). O accumulated as O^T.
// K in LDS [64][64] with 16B-chunk XOR swizzle (chunk ^= kv&7); V^T as u32
// kv-pairs [64 d][32 pair] with pair-XOR swizzle (pair ^= (d&7)<<2); P via
// per-wave LDS [32 q][36 pitch] (b64 writes / b128 reads, same-wave no barrier).
__global__ __launch_bounds__(256) void attn_kernel(const u16* __restrict__ qkv,
                                                   u16* __restrict__ out) {
    __shared__ __align__(16) u16      KsS[64 * 64];       // 8 KB
    __shared__ __align__(16) uint32_t VTs[64 * 32];       // 8 KB
    __shared__ __align__(16) uint32_t PsW[4 * 32 * 36];   // 18 KB

    const int tid  = threadIdx.x;
    const int w    = tid >> 6;
    const int lane = tid & 63;
    const int q32  = lane & 31;
    const int hi   = lane >> 5;

    const int bh = blockIdx.y;
    const int b  = bh >> 4;
    const int h  = bh & 15;
    const int rowbase = b * N_;
    const int qglob = blockIdx.x * 128 + w * 32 + q32;
    const int qoff  = h * DH_;
    const float qs = 0.125f * 1.4426950408889634f;   // DH^-0.5 * log2(e)

    // Q B-frags (raw; scale folded into softmax): qf[ks] = Q[q][ks*16+hi*8 ..+7]
    bf16x8 qf[4];
    {
        const u16* qp = qkv + (size_t)(rowbase + qglob) * QKVN_ + qoff;
#pragma unroll
        for (int ks = 0; ks < 4; ks++)
            qf[ks] = *reinterpret_cast<const bf16x8*>(qp + ks * 16 + hi * 8);
    }

    // hoisted loop-invariant LDS offsets
    int kch[4], vrd[4];
#pragma unroll
    for (int ks = 0; ks < 4; ks++) {
        kch[ks] = ((2 * ks + hi) ^ (q32 & 7)) * 8;                 // KsS chunk (u16 elems)
        vrd[ks] = (ks * 8 + hi * 4) ^ ((q32 & 7) << 2);            // VTs word offset
    }
    const int krowA = q32 * 64;                // kv half 0 row base (u16)
    const int krowB = (32 + q32) * 64;         // kv half 1
    const int vrowA = q32 * 32;                // d-block 0 row base (u32)
    const int vrowB = (32 + q32) * 32;         // d-block 1
    const int psw   = w * 1152 + q32 * 36;     // per-wave P base (u32 words)
    const int pswW  = psw + 2 * hi;            // write base
    const int pswR  = psw + 4 * hi;            // read base

    float mrun = -3e38f, lrun = 0.f;
    f32x16 o0, o1;
#pragma unroll
    for (int r = 0; r < 16; r++) { o0[r] = 0.f; o1[r] = 0.f; }

    const u16* kg = qkv + (size_t)rowbase * QKVN_ + DIM_ + qoff;
    const u16* vg = qkv + (size_t)rowbase * QKVN_ + 2 * DIM_ + qoff;

    // staging maps
    const int kr = tid >> 2, ka = tid & 3;          // K: row kv=kr, d-chunkpair 2ka
    const size_t kgo = (size_t)kr * QKVN_ + ka * 16;
    const int kl0 = kr * 64 + ((2 * ka)     ^ (kr & 7)) * 8;
    const int kl1 = kr * 64 + ((2 * ka + 1) ^ (kr & 7)) * 8;
    const int vp = tid >> 3, vd = (tid & 7) * 8;    // V: kv-pair vp, d base vd
    const size_t vgo0 = (size_t)(2 * vp) * QKVN_ + vd;
    const size_t vgo1 = vgo0 + QKVN_;

    short8 kst0, kst1, vst0, vst1;
    kst0 = *reinterpret_cast<const short8*>(kg + kgo);
    kst1 = *reinterpret_cast<const short8*>(kg + kgo + 8);
    vst0 = *reinterpret_cast<const short8*>(vg + vgo0);
    vst1 = *reinterpret_cast<const short8*>(vg + vgo1);

    *reinterpret_cast<short8*>(&KsS[kl0]) = kst0;
    *reinterpret_cast<short8*>(&KsS[kl1]) = kst1;
    {
        const u16* v0 = reinterpret_cast<const u16*>(&vst0);
        const u16* v1 = reinterpret_cast<const u16*>(&vst1);
#pragma unroll
        for (int i = 0; i < 8; i++)
            VTs[(vd + i) * 32 + (vp ^ (i << 2))] = (uint32_t)v0[i] | ((uint32_t)v1[i] << 16);
    }
    __syncthreads();

    for (int t = 0; t < N_ / 64; t++) {
        // async-STAGE: issue next tile's global loads before compute
        if (t + 1 < N_ / 64) {
            const u16* kg2 = kg + (size_t)(t + 1) * 64 * QKVN_;
            const u16* vg2 = vg + (size_t)(t + 1) * 64 * QKVN_;
            kst0 = *reinterpret_cast<const short8*>(kg2 + kgo);
            kst1 = *reinterpret_cast<const short8*>(kg2 + kgo + 8);
            vst0 = *reinterpret_cast<const short8*>(vg2 + vgo0);
            vst1 = *reinterpret_cast<const short8*>(vg2 + vgo1);
        }

        // ---- S^T = K Q^T (raw logits), lane column q32 ----
        f32x16 sa0, sa1;
#pragma unroll
        for (int r = 0; r < 16; r++) { sa0[r] = 0.f; sa1[r] = 0.f; }
#pragma unroll
        for (int ks = 0; ks < 4; ks++) {
            bf16x8 a0 = *reinterpret_cast<const bf16x8*>(&KsS[krowA + kch[ks]]);
            bf16x8 a1 = *reinterpret_cast<const bf16x8*>(&KsS[krowB + kch[ks]]);
            sa0 = __builtin_amdgcn_mfma_f32_32x32x16_bf16(a0, qf[ks], sa0, 0, 0, 0);
            sa1 = __builtin_amdgcn_mfma_f32_32x32x16_bf16(a1, qf[ks], sa1, 0, 0, 0);
        }

        // ---- per-lane online softmax (exp2 domain) ----
        float tmax = sa0[0];
#pragma unroll
        for (int r = 1; r < 16; r++) tmax = fmaxf(tmax, sa0[r]);
#pragma unroll
        for (int r = 0; r < 16; r++) tmax = fmaxf(tmax, sa1[r]);
        tmax = fmaxf(tmax, __shfl_xor(tmax, 32));
        const float ts = tmax * qs;

        if (!__all(ts - mrun <= 8.f)) {
            float mnew = fmaxf(mrun, ts);
            float fac  = exp2f(mrun - mnew);
            mrun = mnew;
            lrun *= fac;
#pragma unroll
            for (int r = 0; r < 16; r++) { o0[r] *= fac; o1[r] *= fac; }
        }

        float psum = 0.f;
#pragma unroll
        for (int r = 0; r < 16; r++) {
            sa0[r] = exp2f(__builtin_fmaf(sa0[r], qs, -mrun));
            psum += sa0[r];
        }
#pragma unroll
        for (int r = 0; r < 16; r++) {
            sa1[r] = exp2f(__builtin_fmaf(sa1[r], qs, -mrun));
            psum += sa1[r];
        }
        psum += __shfl_xor(psum, 32);
        lrun += psum;

        // ---- P -> per-wave LDS (b64 writes; kv quads) ----
#pragma unroll
        for (int j = 0; j < 4; j++) {
            u16x4 pw;
            pw.x = f2bf(sa0[4 * j + 0]); pw.y = f2bf(sa0[4 * j + 1]);
            pw.z = f2bf(sa0[4 * j + 2]); pw.w = f2bf(sa0[4 * j + 3]);
            *reinterpret_cast<u16x4*>(&PsW[pswW + 4 * j]) = pw;
        }
#pragma unroll
        for (int j = 0; j < 4; j++) {
            u16x4 pw;
            pw.x = f2bf(sa1[4 * j + 0]); pw.y = f2bf(sa1[4 * j + 1]);
            pw.z = f2bf(sa1[4 * j + 2]); pw.w = f2bf(sa1[4 * j + 3]);
            *reinterpret_cast<u16x4*>(&PsW[pswW + 16 + 4 * j]) = pw;
        }

        // ---- O^T += V^T P^T ----
#pragma unroll
        for (int ks = 0; ks < 4; ks++) {
            bf16x8 pb  = *reinterpret_cast<const bf16x8*>(&PsW[pswR + ks * 8]);
            bf16x8 va0 = *reinterpret_cast<const bf16x8*>(&VTs[vrowA + vrd[ks]]);
            bf16x8 va1 = *reinterpret_cast<const bf16x8*>(&VTs[vrowB + vrd[ks]]);
            o0 = __builtin_amdgcn_mfma_f32_32x32x16_bf16(va0, pb, o0, 0, 0, 0);
            o1 = __builtin_amdgcn_mfma_f32_32x32x16_bf16(va1, pb, o1, 0, 0, 0);
        }

        __syncthreads();
        if (t + 1 < N_ / 64) {
            *reinterpret_cast<short8*>(&KsS[kl0]) = kst0;
            *reinterpret_cast<short8*>(&KsS[kl1]) = kst1;
            const u16* v0 = reinterpret_cast<const u16*>(&vst0);
            const u16* v1 = reinterpret_cast<const u16*>(&vst1);
#pragma unroll
            for (int i = 0; i < 8; i++)
                VTs[(vd + i) * 32 + (vp ^ (i << 2))] = (uint32_t)v0[i] | ((uint32_t)v1[i] << 16);
        }
        __syncthreads();
    }

    // ---- write O[q][d] = O^T / lrun ; per-lane scalar normalizer ----
    const float linv = 1.f / lrun;
    u16* orow = out + (size_t)(rowbase + qglob) * DIM_ + qoff;
#pragma unroll
    for (int j = 0; j < 4; j++) {
        u16x4 ov;
        ov.x = f2bf(o0[4 * j + 0] * linv); ov.y = f2bf(o0[4 * j + 1] * linv);
        ov.z = f2bf(o0[4 * j + 2] * linv); ov.w = f2bf(o0[4 * j + 3] * linv);
        *reinterpret_cast<u16x4*>(&orow[8 * j + 4 * hi]) = ov;
        u16x4 ow;
        ow.x = f2bf(o1[4 * j + 0] * linv); ow.y = f2bf(o1[4 * j + 1] * linv);
        ow.z = f2bf(o1[4 * j + 2] * linv); ow.w = f2bf(o1[4 * j + 3] * linv);
        *reinterpret_cast<u16x4*>(&orow[32 + 8 * j + 4 * hi]) = ow;
    }
}

// ---------------- launcher ----------------
extern "C" void kernel_launch(void* const* d_in, const int* in_sizes, int n_in,
                              void* d_out, int out_size, void* d_ws, size_t ws_size,
                              hipStream_t stream) {
    const float* x     = (const float*)d_in[0];
    const float* w_qkv = (const float*)d_in[1];
    const float* w_out = (const float*)d_in[2];
    const float* b_out = (const float*)d_in[3];
    float* out = (float*)d_out;

    char* ws = (char*)d_ws;
    u16* xbf   = (u16*)(ws);                       // 8192*1024  bf16 = 16 MiB
    u16* wqkvT = (u16*)(ws + 16777216);            // 3072*1024  bf16 =  6 MiB
    u16* woutT = (u16*)(ws + 23068672);            // 1024*1024  bf16 =  2 MiB
    u16* qkv   = (u16*)(ws + 25165824);            // 8192*3072  bf16 = 48 MiB
    u16* attnO = (u16*)(ws + 75497472);            // 8192*1024  bf16 = 16 MiB

    cast_f32_bf16<<<2048, 256, 0, stream>>>(x, xbf, (BN_ * DIM_) / 4);
    transpose_cast<<<(DIM_ / 4) * QKVN_ / 256, 256, 0, stream>>>(w_qkv, wqkvT, DIM_, QKVN_);
    transpose_cast<<<(DIM_ / 4) * DIM_ / 256, 256, 0, stream>>>(w_out, woutT, DIM_, DIM_);

    gemm_bt<true><<<dim3(QKVN_ / 128, BN_ / 128), 256, 0, stream>>>(
        xbf, wqkvT, qkv, nullptr, BN_, QKVN_, DIM_);

    attn_kernel<<<dim3(N_ / 128, B_ * H_), 256, 0, stream>>>(qkv, attnO);

    gemm_bt<false><<<dim3(DIM_ / 128, BN_ / 128), 256, 0, stream>>>(
        attnO, woutT, out, b_out, BN_, DIM_, DIM_);
}

// Round 7
// 317.169 us; speedup vs baseline: 1.9277x; 1.0931x over previous
//
#include <hip/hip_runtime.h>
#include <stdint.h>

#define B_    4
#define N_    2048
#define DIM_  1024
#define H_    16
#define DH_   64
#define BN_   (B_ * N_)        // 8192 rows
#define QKVN_ (3 * H_ * DH_)   // 3072 qkv cols

#define AS1_ __attribute__((address_space(1)))
#define AS3_ __attribute__((address_space(3)))

typedef unsigned short u16;
typedef __attribute__((ext_vector_type(8)))  __bf16 bf16x8;
typedef __attribute__((ext_vector_type(8)))  short  short8;
typedef __attribute__((ext_vector_type(4)))  float  f32x4;
typedef __attribute__((ext_vector_type(16))) float  f32x16;
typedef __attribute__((ext_vector_type(4)))  u16    u16x4;

__device__ inline u16 f2bf(float f) {            // native RNE cast (cvt_pk-able)
    union { __bf16 b; u16 u; } v; v.b = (__bf16)f; return v.u;
}
__device__ inline float bf2f(u16 u) {
    union { uint32_t u; float f; } v; v.u = ((uint32_t)u) << 16;
    return v.f;
}
__device__ inline int xcd_swz(int bid, int nwg) {   // bijective when nwg%8==0
    return (bid & 7) * (nwg >> 3) + (bid >> 3);
}

// ---------------- elementwise cast fp32 -> bf16 ----------------
__global__ __launch_bounds__(256) void cast_f32_bf16(const float* __restrict__ in,
                                                     u16* __restrict__ out, int n4) {
    int i = blockIdx.x * blockDim.x + threadIdx.x;
    int stride = gridDim.x * blockDim.x;
    for (; i < n4; i += stride) {
        float4 v = reinterpret_cast<const float4*>(in)[i];
        u16x4 o;
        o.x = f2bf(v.x); o.y = f2bf(v.y); o.z = f2bf(v.z); o.w = f2bf(v.w);
        reinterpret_cast<u16x4*>(out)[i] = o;
    }
}

// -------- cast + transpose: in[R][C] fp32 -> out[C][R] bf16 --------
__global__ __launch_bounds__(256) void transpose_cast(const float* __restrict__ in,
                                                      u16* __restrict__ out, int R, int C) {
    int gid = blockIdx.x * blockDim.x + threadIdx.x;
    int total = C * (R / 4);
    if (gid >= total) return;
    int n  = gid % C;
    int k4 = (gid / C) * 4;
    u16x4 o;
    o.x = f2bf(in[(size_t)(k4 + 0) * C + n]);
    o.y = f2bf(in[(size_t)(k4 + 1) * C + n]);
    o.z = f2bf(in[(size_t)(k4 + 2) * C + n]);
    o.w = f2bf(in[(size_t)(k4 + 3) * C + n]);
    *reinterpret_cast<u16x4*>(&out[(size_t)n * R + k4]) = o;
}

// ---------------- GEMM: C[M,N] = A[M,K] * BT[N,K]^T  (m97 structure) --------
// 1D grid with XCD swizzle; 128x128 tile, BK=32, global_load_lds width=16.
template <bool BF16_OUT>
__global__ __launch_bounds__(256) void gemm_bt(const u16* __restrict__ A,
                                               const u16* __restrict__ BT,
                                               void* __restrict__ Cout,
                                               const float* __restrict__ bias,
                                               int M, int Nn, int K) {
    __shared__ __align__(16) u16 AsF[128 * 32];   // 8 KB
    __shared__ __align__(16) u16 BsF[128 * 32];   // 8 KB

    const int nbx = Nn >> 7;
    int bid = blockIdx.x;
    if ((gridDim.x & 7) == 0) bid = xcd_swz(bid, gridDim.x);
    const int m0 = (bid / nbx) * 128;
    const int n0 = (bid % nbx) * 128;

    const int tid  = threadIdx.x;
    const int w    = tid >> 6;
    const int lane = tid & 63;
    const int lr   = lane & 15;
    const int lg   = lane >> 4;
    const int wm   = w >> 1;
    const int wn   = w & 1;

    f32x4 acc[4][4] = {};

    const int sr = tid >> 2;
    const int sc = (tid & 3) * 8;
    const u16* Aptr = A  + (size_t)(m0 + sr) * K + sc;
    const u16* Bptr = BT + (size_t)(n0 + sr) * K + sc;
    const int ldsb = w * 512;

    for (int kt = 0; kt < K; kt += 32) {
        __builtin_amdgcn_global_load_lds((const AS1_ void*)(Aptr + kt),
                                         (AS3_ void*)&AsF[ldsb], 16, 0, 0);
        __builtin_amdgcn_global_load_lds((const AS1_ void*)(Aptr + (size_t)64 * K + kt),
                                         (AS3_ void*)&AsF[2048 + ldsb], 16, 0, 0);
        __builtin_amdgcn_global_load_lds((const AS1_ void*)(Bptr + kt),
                                         (AS3_ void*)&BsF[ldsb], 16, 0, 0);
        __builtin_amdgcn_global_load_lds((const AS1_ void*)(Bptr + (size_t)64 * K + kt),
                                         (AS3_ void*)&BsF[2048 + ldsb], 16, 0, 0);
        __syncthreads();

        bf16x8 af[4], bfr[4];
#pragma unroll
        for (int m = 0; m < 4; m++)
            af[m] = *reinterpret_cast<const bf16x8*>(&AsF[(wm * 64 + m * 16 + lr) * 32 + lg * 8]);
#pragma unroll
        for (int n = 0; n < 4; n++)
            bfr[n] = *reinterpret_cast<const bf16x8*>(&BsF[(wn * 64 + n * 16 + lr) * 32 + lg * 8]);
        __builtin_amdgcn_s_setprio(1);
#pragma unroll
        for (int m = 0; m < 4; m++)
#pragma unroll
            for (int n = 0; n < 4; n++)
                acc[m][n] = __builtin_amdgcn_mfma_f32_16x16x32_bf16(af[m], bfr[n], acc[m][n], 0, 0, 0);
        __builtin_amdgcn_s_setprio(0);
        __syncthreads();
    }

#pragma unroll
    for (int m = 0; m < 4; m++)
#pragma unroll
        for (int n = 0; n < 4; n++) {
            const int row = m0 + wm * 64 + m * 16 + lg * 4;
            const int col = n0 + wn * 64 + n * 16 + lr;
#pragma unroll
            for (int r = 0; r < 4; r++) {
                if (BF16_OUT) {
                    ((u16*)Cout)[(size_t)(row + r) * Nn + col] = f2bf(acc[m][n][r]);
                } else {
                    ((float*)Cout)[(size_t)(row + r) * Nn + col] = acc[m][n][r] + bias[col];
                }
            }
        }
}

// ---------------- flash attention v7: per-lane-q 32x32 structure ----------------
// v6 + (a) conflict-free V-staging layout: col(d,pair) = pair ^ φ(d),
// φ(d) = (((d>>3)+d)&7)<<2 — write octets (d = 8k+i) AND read octets
// (d = q32 consecutive) both span 8 distinct bank-groups; (b) max3 trees;
// (c) s_setprio around MFMA clusters; (d) XCD-swizzled 1D grid.
__global__ __launch_bounds__(256) void attn_kernel(const u16* __restrict__ qkv,
                                                   u16* __restrict__ out) {
    __shared__ __align__(16) u16      KsS[64 * 64];       // 8 KB
    __shared__ __align__(16) uint32_t VTs[64 * 32];       // 8 KB
    __shared__ __align__(16) uint32_t PsW[4 * 32 * 36];   // 18 KB

    const int tid  = threadIdx.x;
    const int w    = tid >> 6;
    const int lane = tid & 63;
    const int q32  = lane & 31;
    const int hi   = lane >> 5;

    int bid = xcd_swz(blockIdx.x, gridDim.x);
    const int bh = bid >> 4;           // 0..63
    const int b  = bh >> 4;
    const int h  = bh & 15;
    const int rowbase = b * N_;
    const int qglob = (bid & 15) * 128 + w * 32 + q32;
    const int qoff  = h * DH_;
    const float qs = 0.125f * 1.4426950408889634f;   // DH^-0.5 * log2(e)

    // Q B-frags (raw; scale folded into softmax fma)
    bf16x8 qf[4];
    {
        const u16* qp = qkv + (size_t)(rowbase + qglob) * QKVN_ + qoff;
#pragma unroll
        for (int ks = 0; ks < 4; ks++)
            qf[ks] = *reinterpret_cast<const bf16x8*>(qp + ks * 16 + hi * 8);
    }

    // hoisted loop-invariant LDS offsets
    int kch[4], vrd0[4], vrd1[4];
    const int f0 = (((q32 >> 3) + q32) & 7) << 2;
    const int f1 = (((q32 >> 3) + q32 + 4) & 7) << 2;
#pragma unroll
    for (int ks = 0; ks < 4; ks++) {
        kch[ks]  = ((2 * ks + hi) ^ (q32 & 7)) * 8;                // KsS chunk (u16)
        vrd0[ks] = q32 * 32        + ((ks * 8 + hi * 4) ^ f0);     // VTs words
        vrd1[ks] = (32 + q32) * 32 + ((ks * 8 + hi * 4) ^ f1);
    }
    const int krowA = q32 * 64;
    const int krowB = (32 + q32) * 64;
    const int psw   = w * 1152 + q32 * 36;
    const int pswW  = psw + 2 * hi;
    const int pswR  = psw + 4 * hi;

    float mrun = -3e38f, lrun = 0.f;
    f32x16 o0, o1;
#pragma unroll
    for (int r = 0; r < 16; r++) { o0[r] = 0.f; o1[r] = 0.f; }

    const u16* kg = qkv + (size_t)rowbase * QKVN_ + DIM_ + qoff;
    const u16* vg = qkv + (size_t)rowbase * QKVN_ + 2 * DIM_ + qoff;

    // staging maps
    const int kr = tid >> 2, ka = tid & 3;
    const size_t kgo = (size_t)kr * QKVN_ + ka * 16;
    const int kl0 = kr * 64 + ((2 * ka)     ^ (kr & 7)) * 8;
    const int kl1 = kr * 64 + ((2 * ka + 1) ^ (kr & 7)) * 8;
    const int vp = tid >> 3, vk = tid & 7;          // V: kv-pair vp, d-octet vk
    const size_t vgo0 = (size_t)(2 * vp) * QKVN_ + vk * 8;
    const size_t vgo1 = vgo0 + QKVN_;

    short8 kst0, kst1, vst0, vst1;
    kst0 = *reinterpret_cast<const short8*>(kg + kgo);
    kst1 = *reinterpret_cast<const short8*>(kg + kgo + 8);
    vst0 = *reinterpret_cast<const short8*>(vg + vgo0);
    vst1 = *reinterpret_cast<const short8*>(vg + vgo1);

    *reinterpret_cast<short8*>(&KsS[kl0]) = kst0;
    *reinterpret_cast<short8*>(&KsS[kl1]) = kst1;
    {
        const u16* v0 = reinterpret_cast<const u16*>(&vst0);
        const u16* v1 = reinterpret_cast<const u16*>(&vst1);
#pragma unroll
        for (int i = 0; i < 8; i++)
            VTs[(vk * 8 + i) * 32 + (vp ^ (((vk + i) & 7) << 2))] =
                (uint32_t)v0[i] | ((uint32_t)v1[i] << 16);
    }
    __syncthreads();

    for (int t = 0; t < N_ / 64; t++) {
        // async-STAGE: issue next tile's global loads before compute
        if (t + 1 < N_ / 64) {
            const u16* kg2 = kg + (size_t)(t + 1) * 64 * QKVN_;
            const u16* vg2 = vg + (size_t)(t + 1) * 64 * QKVN_;
            kst0 = *reinterpret_cast<const short8*>(kg2 + kgo);
            kst1 = *reinterpret_cast<const short8*>(kg2 + kgo + 8);
            vst0 = *reinterpret_cast<const short8*>(vg2 + vgo0);
            vst1 = *reinterpret_cast<const short8*>(vg2 + vgo1);
        }

        // ---- S^T = K Q^T (raw logits), lane column q32 ----
        f32x16 sa0, sa1;
#pragma unroll
        for (int r = 0; r < 16; r++) { sa0[r] = 0.f; sa1[r] = 0.f; }
        __builtin_amdgcn_s_setprio(1);
#pragma unroll
        for (int ks = 0; ks < 4; ks++) {
            bf16x8 a0 = *reinterpret_cast<const bf16x8*>(&KsS[krowA + kch[ks]]);
            bf16x8 a1 = *reinterpret_cast<const bf16x8*>(&KsS[krowB + kch[ks]]);
            sa0 = __builtin_amdgcn_mfma_f32_32x32x16_bf16(a0, qf[ks], sa0, 0, 0, 0);
            sa1 = __builtin_amdgcn_mfma_f32_32x32x16_bf16(a1, qf[ks], sa1, 0, 0, 0);
        }
        __builtin_amdgcn_s_setprio(0);

        // ---- per-lane online softmax (exp2 domain), max3-friendly trees ----
        float m0a = fmaxf(fmaxf(sa0[0], sa0[1]), sa0[2]);
        float m1a = fmaxf(fmaxf(sa0[3], sa0[4]), sa0[5]);
        float m2a = fmaxf(fmaxf(sa0[6], sa0[7]), sa0[8]);
        float m3a = fmaxf(fmaxf(sa0[9], sa0[10]), sa0[11]);
        float m4a = fmaxf(fmaxf(sa0[12], sa0[13]), sa0[14]);
        float m5a = fmaxf(fmaxf(sa0[15], sa1[0]), sa1[1]);
        float m6a = fmaxf(fmaxf(sa1[2], sa1[3]), sa1[4]);
        float m7a = fmaxf(fmaxf(sa1[5], sa1[6]), sa1[7]);
        float m8a = fmaxf(fmaxf(sa1[8], sa1[9]), sa1[10]);
        float m9a = fmaxf(fmaxf(sa1[11], sa1[12]), sa1[13]);
        float mAa = fmaxf(sa1[14], sa1[15]);
        float t0 = fmaxf(fmaxf(m0a, m1a), m2a);
        float t1 = fmaxf(fmaxf(m3a, m4a), m5a);
        float t2 = fmaxf(fmaxf(m6a, m7a), m8a);
        float t3 = fmaxf(m9a, mAa);
        float tmax = fmaxf(fmaxf(t0, t1), fmaxf(t2, t3));
        tmax = fmaxf(tmax, __shfl_xor(tmax, 32));
        const float ts = tmax * qs;

        if (!__all(ts - mrun <= 8.f)) {
            float mnew = fmaxf(mrun, ts);
            float fac  = exp2f(mrun - mnew);
            mrun = mnew;
            lrun *= fac;
#pragma unroll
            for (int r = 0; r < 16; r++) { o0[r] *= fac; o1[r] *= fac; }
        }

        float psum = 0.f;
#pragma unroll
        for (int r = 0; r < 16; r++) {
            sa0[r] = exp2f(__builtin_fmaf(sa0[r], qs, -mrun));
            psum += sa0[r];
        }
#pragma unroll
        for (int r = 0; r < 16; r++) {
            sa1[r] = exp2f(__builtin_fmaf(sa1[r], qs, -mrun));
            psum += sa1[r];
        }
        psum += __shfl_xor(psum, 32);
        lrun += psum;

        // ---- P -> per-wave LDS (b64 writes; kv quads) ----
#pragma unroll
        for (int j = 0; j < 4; j++) {
            u16x4 pw;
            pw.x = f2bf(sa0[4 * j + 0]); pw.y = f2bf(sa0[4 * j + 1]);
            pw.z = f2bf(sa0[4 * j + 2]); pw.w = f2bf(sa0[4 * j + 3]);
            *reinterpret_cast<u16x4*>(&PsW[pswW + 4 * j]) = pw;
        }
#pragma unroll
        for (int j = 0; j < 4; j++) {
            u16x4 pw;
            pw.x = f2bf(sa1[4 * j + 0]); pw.y = f2bf(sa1[4 * j + 1]);
            pw.z = f2bf(sa1[4 * j + 2]); pw.w = f2bf(sa1[4 * j + 3]);
            *reinterpret_cast<u16x4*>(&PsW[pswW + 16 + 4 * j]) = pw;
        }

        // ---- O^T += V^T P^T ----
        __builtin_amdgcn_s_setprio(1);
#pragma unroll
        for (int ks = 0; ks < 4; ks++) {
            bf16x8 pb  = *reinterpret_cast<const bf16x8*>(&PsW[pswR + ks * 8]);
            bf16x8 va0 = *reinterpret_cast<const bf16x8*>(&VTs[vrd0[ks]]);
            bf16x8 va1 = *reinterpret_cast<const bf16x8*>(&VTs[vrd1[ks]]);
            o0 = __builtin_amdgcn_mfma_f32_32x32x16_bf16(va0, pb, o0, 0, 0, 0);
            o1 = __builtin_amdgcn_mfma_f32_32x32x16_bf16(va1, pb, o1, 0, 0, 0);
        }
        __builtin_amdgcn_s_setprio(0);

        __syncthreads();
        if (t + 1 < N_ / 64) {
            *reinterpret_cast<short8*>(&KsS[kl0]) = kst0;
            *reinterpret_cast<short8*>(&KsS[kl1]) = kst1;
            const u16* v0 = reinterpret_cast<const u16*>(&vst0);
            const u16* v1 = reinterpret_cast<const u16*>(&vst1);
#pragma unroll
            for (int i = 0; i < 8; i++)
                VTs[(vk * 8 + i) * 32 + (vp ^ (((vk + i) & 7) << 2))] =
                    (uint32_t)v0[i] | ((uint32_t)v1[i] << 16);
        }
        __syncthreads();
    }

    // ---- write O[q][d] = O^T / lrun ; per-lane scalar normalizer ----
    const float linv = 1.f / lrun;
    u16* orow = out + (size_t)(rowbase + qglob) * DIM_ + qoff;
#pragma unroll
    for (int j = 0; j < 4; j++) {
        u16x4 ov;
        ov.x = f2bf(o0[4 * j + 0] * linv); ov.y = f2bf(o0[4 * j + 1] * linv);
        ov.z = f2bf(o0[4 * j + 2] * linv); ov.w = f2bf(o0[4 * j + 3] * linv);
        *reinterpret_cast<u16x4*>(&orow[8 * j + 4 * hi]) = ov;
        u16x4 ow;
        ow.x = f2bf(o1[4 * j + 0] * linv); ow.y = f2bf(o1[4 * j + 1] * linv);
        ow.z = f2bf(o1[4 * j + 2] * linv); ow.w = f2bf(o1[4 * j + 3] * linv);
        *reinterpret_cast<u16x4*>(&orow[32 + 8 * j + 4 * hi]) = ow;
    }
}

// ---------------- launcher ----------------
extern "C" void kernel_launch(void* const* d_in, const int* in_sizes, int n_in,
                              void* d_out, int out_size, void* d_ws, size_t ws_size,
                              hipStream_t stream) {
    const float* x     = (const float*)d_in[0];
    const float* w_qkv = (const float*)d_in[1];
    const float* w_out = (const float*)d_in[2];
    const float* b_out = (const float*)d_in[3];
    float* out = (float*)d_out;

    char* ws = (char*)d_ws;
    u16* xbf   = (u16*)(ws);                       // 8192*1024  bf16 = 16 MiB
    u16* wqkvT = (u16*)(ws + 16777216);            // 3072*1024  bf16 =  6 MiB
    u16* woutT = (u16*)(ws + 23068672);            // 1024*1024  bf16 =  2 MiB
    u16* qkv   = (u16*)(ws + 25165824);            // 8192*3072  bf16 = 48 MiB
    u16* attnO = (u16*)(ws + 75497472);            // 8192*1024  bf16 = 16 MiB

    cast_f32_bf16<<<2048, 256, 0, stream>>>(x, xbf, (BN_ * DIM_) / 4);
    transpose_cast<<<(DIM_ / 4) * QKVN_ / 256, 256, 0, stream>>>(w_qkv, wqkvT, DIM_, QKVN_);
    transpose_cast<<<(DIM_ / 4) * DIM_ / 256, 256, 0, stream>>>(w_out, woutT, DIM_, DIM_);

    gemm_bt<true><<<(QKVN_ / 128) * (BN_ / 128), 256, 0, stream>>>(
        xbf, wqkvT, qkv, nullptr, BN_, QKVN_, DIM_);

    attn_kernel<<<(N_ / 128) * (B_ * H_), 256, 0, stream>>>(qkv, attnO);

    gemm_bt<false><<<(DIM_ / 128) * (BN_ / 128), 256, 0, stream>>>(
        attnO, woutT, out, b_out, BN_, DIM_, DIM_);
}